// Round 1
// baseline (141.112 us; speedup 1.0000x reference)
//
#include <hip/hip_runtime.h>

// Problem constants (from setup_inputs): B=8, N=M=4096, D=3, fp32.
constexpr int B = 8;
constexpr int N = 4096;
constexpr int M = 4096;

#define TPB 256      // threads per block (one "own" point per thread)
#define CHUNK 512    // "other" points staged in LDS per block (8 KB as float4)

// Initialize min-d2 arrays to +inf (bit pattern 0x7F800000). For non-negative
// floats, uint bit-pattern ordering == float ordering, so atomicMin on uint works.
__global__ void init_min(unsigned int* __restrict__ p, int n) {
    int i = blockIdx.x * blockDim.x + threadIdx.x;
    if (i < n) p[i] = 0x7F800000u;
}

// For each (b, i) over `own`, compute min over a CHUNK of `oth` of squared
// distance; atomicMin the partial into outbits[b*Nown + i].
__global__ __launch_bounds__(TPB) void chamfer_min(
        const float* __restrict__ own,   // (B, Nown, 3)
        const float* __restrict__ oth,   // (B, Noth, 3)
        unsigned int* __restrict__ outbits, // (B*Nown) min d2 as uint bits
        int Nown, int Noth) {
    __shared__ float4 ys[CHUNK];

    const int b     = blockIdx.z;
    const int i     = blockIdx.x * TPB + threadIdx.x;
    const int jbase = blockIdx.y * CHUNK;

    // Stage the chunk of "other" points into LDS as float4 (16B-aligned reads later).
    const float* op = oth + ((size_t)b * Noth + jbase) * 3;
    for (int t = threadIdx.x; t < CHUNK; t += TPB) {
        ys[t] = make_float4(op[3 * t], op[3 * t + 1], op[3 * t + 2], 0.0f);
    }

    // Own point.
    const float* pp = own + ((size_t)b * Nown + i) * 3;
    const float px = pp[0], py = pp[1], pz = pp[2];

    __syncthreads();

    // 4 independent min accumulators to break the fmin dependency chain.
    float b0 = 3.4e38f, b1 = 3.4e38f, b2 = 3.4e38f, b3 = 3.4e38f;
    #pragma unroll 2
    for (int j = 0; j < CHUNK; j += 4) {
        float4 q0 = ys[j + 0];
        float4 q1 = ys[j + 1];
        float4 q2 = ys[j + 2];
        float4 q3 = ys[j + 3];

        float dx0 = px - q0.x, dy0 = py - q0.y, dz0 = pz - q0.z;
        float dx1 = px - q1.x, dy1 = py - q1.y, dz1 = pz - q1.z;
        float dx2 = px - q2.x, dy2 = py - q2.y, dz2 = pz - q2.z;
        float dx3 = px - q3.x, dy3 = py - q3.y, dz3 = pz - q3.z;

        float d0 = fmaf(dx0, dx0, fmaf(dy0, dy0, dz0 * dz0));
        float d1 = fmaf(dx1, dx1, fmaf(dy1, dy1, dz1 * dz1));
        float d2 = fmaf(dx2, dx2, fmaf(dy2, dy2, dz2 * dz2));
        float d3 = fmaf(dx3, dx3, fmaf(dy3, dy3, dz3 * dz3));

        b0 = fminf(b0, d0);
        b1 = fminf(b1, d1);
        b2 = fminf(b2, d2);
        b3 = fminf(b3, d3);
    }
    float best = fminf(fminf(b0, b1), fminf(b2, b3));

    atomicMin(&outbits[(size_t)b * Nown + i], __float_as_uint(best));
}

// Final: out = sum_i sqrt(eps + d2_i) * scale over both min arrays (contiguous).
// mean(min1) + mean(min2) with B*N == B*M means one combined sum * 1/(B*N).
__global__ __launch_bounds__(1024) void chamfer_reduce(
        const unsigned int* __restrict__ bits,
        float* __restrict__ out, int total, float scale) {
    float s = 0.0f;
    for (int i = threadIdx.x; i < total; i += 1024) {
        float d2 = __uint_as_float(bits[i]);
        s += sqrtf(1e-8f + d2);
    }
    // wave (64-lane) reduction
    #pragma unroll
    for (int off = 32; off > 0; off >>= 1) s += __shfl_down(s, off, 64);

    __shared__ float partial[16];
    const int wid = threadIdx.x >> 6, lane = threadIdx.x & 63;
    if (lane == 0) partial[wid] = s;
    __syncthreads();
    if (threadIdx.x < 16) {
        float v = partial[threadIdx.x];
        #pragma unroll
        for (int off = 8; off > 0; off >>= 1) v += __shfl_down(v, off, 16);
        if (threadIdx.x == 0) out[0] = v * scale;
    }
}

extern "C" void kernel_launch(void* const* d_in, const int* in_sizes, int n_in,
                              void* d_out, int out_size, void* d_ws, size_t ws_size,
                              hipStream_t stream) {
    const float* x1 = (const float*)d_in[0];   // (B, N, 3)
    const float* y1 = (const float*)d_in[1];   // (B, M, 3)
    float* out = (float*)d_out;                // scalar

    unsigned int* min1 = (unsigned int*)d_ws;  // B*N floats (as uint bits)
    unsigned int* min2 = min1 + (size_t)B * N; // B*M
    const int total = B * N + B * M;           // 65536

    // 1) init min arrays to +inf (ws is poisoned 0xAA each call)
    init_min<<<(total + 255) / 256, 256, 0, stream>>>(min1, total);

    // 2) min over y for each x  -> min1
    dim3 grid1(N / TPB, M / CHUNK, B);
    chamfer_min<<<grid1, TPB, 0, stream>>>(x1, y1, min1, N, M);

    // 3) min over x for each y  -> min2
    dim3 grid2(M / TPB, N / CHUNK, B);
    chamfer_min<<<grid2, TPB, 0, stream>>>(y1, x1, min2, M, N);

    // 4) sqrt + mean(min1) + mean(min2)
    chamfer_reduce<<<1, 1024, 0, stream>>>(min1, out, total, 1.0f / (B * N));
}

// Round 2
// 100.380 us; speedup vs baseline: 1.4058x; 1.4058x over previous
//
#include <hip/hip_runtime.h>

// B=8, N=M=4096, D=3, fp32 in/out.
constexpr int B = 8;
constexpr int N = 4096;   // == M

#define TPB 256      // threads per block
#define R 4          // own points per thread -> 1024 own pts per block
#define CHUNK 256    // "other" points staged in LDS per block (4 KB float4)
#define NCHUNK (N / CHUNK)   // 16
#define NTILE (N / (TPB * R)) // 4 own-tiles per batch

// Init min arrays to +inf bits. Non-negative floats: uint order == float order.
__global__ void init_min(unsigned int* __restrict__ p, int n) {
    int i = blockIdx.x * blockDim.x + threadIdx.x;
    if (i < n) p[i] = 0x7F800000u;
}

// Merged both-direction kernel.
// blockIdx.x: own-tile (0..NTILE-1), blockIdx.z: batch,
// blockIdx.y in [0, 2*NCHUNK): dir = y / NCHUNK, chunk = y % NCHUNK.
// dir 0: own=x (min over y); dir 1: own=y (min over x).
__global__ __launch_bounds__(TPB) void chamfer_min2(
        const float* __restrict__ x1,    // (B, N, 3)
        const float* __restrict__ y1,    // (B, N, 3)
        unsigned int* __restrict__ outbits) { // [2][B][N] min d2 bits
    __shared__ float4 ys[CHUNK];

    const int dir   = blockIdx.y / NCHUNK;
    const int chunk = blockIdx.y % NCHUNK;
    const int b     = blockIdx.z;
    const int tile  = blockIdx.x;

    const float* own = dir ? y1 : x1;
    const float* oth = dir ? x1 : y1;
    unsigned int* obits = outbits + (size_t)dir * B * N + (size_t)b * N;

    // Stage CHUNK other-points: float4(qx, qy, qz, |q|^2).
    const float* op = oth + ((size_t)b * N + chunk * CHUNK) * 3;
    if (threadIdx.x < CHUNK) {
        int t = threadIdx.x;
        float qx = op[3 * t], qy = op[3 * t + 1], qz = op[3 * t + 2];
        float qq = fmaf(qx, qx, fmaf(qy, qy, qz * qz));
        ys[t] = make_float4(qx, qy, qz, qq);
    }

    // R own points, strided by TPB for coalescing.
    const int ibase = tile * (TPB * R) + threadIdx.x;
    float mx[R], my[R], mz[R], xx[R], acc[R];
    #pragma unroll
    for (int r = 0; r < R; r++) {
        const float* pp = own + ((size_t)b * N + ibase + r * TPB) * 3;
        float px = pp[0], py = pp[1], pz = pp[2];
        mx[r] = -2.0f * px; my[r] = -2.0f * py; mz[r] = -2.0f * pz;
        xx[r] = fmaf(px, px, fmaf(py, py, pz * pz));
        acc[r] = 3.4e38f;
    }

    __syncthreads();

    // Inner loop: 3 FMA + 1 min per pair (Gram form; |q|^2 pre-staged in .w).
    #pragma unroll 4
    for (int j = 0; j < CHUNK; j++) {
        float4 q = ys[j];
        #pragma unroll
        for (int r = 0; r < R; r++) {
            float g = fmaf(mx[r], q.x, fmaf(my[r], q.y, fmaf(mz[r], q.z, q.w)));
            acc[r] = fminf(acc[r], g);
        }
    }

    #pragma unroll
    for (int r = 0; r < R; r++) {
        float d2 = fmaxf(acc[r] + xx[r], 0.0f);   // clamp like the reference
        atomicMin(&obits[ibase + r * TPB], __float_as_uint(d2));
    }
}

// out = (1/(B*N)) * sum_i sqrt(eps + d2_i) over both directions' min arrays.
__global__ __launch_bounds__(1024) void chamfer_reduce(
        const unsigned int* __restrict__ bits,
        float* __restrict__ out, int total, float scale) {
    float s = 0.0f;
    for (int i = threadIdx.x; i < total; i += 1024) {
        float d2 = __uint_as_float(bits[i]);
        s += sqrtf(1e-8f + d2);
    }
    #pragma unroll
    for (int off = 32; off > 0; off >>= 1) s += __shfl_down(s, off, 64);

    __shared__ float partial[16];
    const int wid = threadIdx.x >> 6, lane = threadIdx.x & 63;
    if (lane == 0) partial[wid] = s;
    __syncthreads();
    if (threadIdx.x < 16) {
        float v = partial[threadIdx.x];
        #pragma unroll
        for (int off = 8; off > 0; off >>= 1) v += __shfl_down(v, off, 16);
        if (threadIdx.x == 0) out[0] = v * scale;
    }
}

extern "C" void kernel_launch(void* const* d_in, const int* in_sizes, int n_in,
                              void* d_out, int out_size, void* d_ws, size_t ws_size,
                              hipStream_t stream) {
    const float* x1 = (const float*)d_in[0];   // (B, N, 3)
    const float* y1 = (const float*)d_in[1];   // (B, N, 3)
    float* out = (float*)d_out;

    unsigned int* minbits = (unsigned int*)d_ws; // [2][B][N]
    const int total = 2 * B * N;                 // 65536

    init_min<<<(total + 255) / 256, 256, 0, stream>>>(minbits, total);

    dim3 grid(NTILE, 2 * NCHUNK, B);             // 4 x 32 x 8 = 1024 blocks
    chamfer_min2<<<grid, TPB, 0, stream>>>(x1, y1, minbits);

    chamfer_reduce<<<1, 1024, 0, stream>>>(minbits, out, total, 1.0f / (B * N));
}

// Round 3
// 84.687 us; speedup vs baseline: 1.6663x; 1.1853x over previous
//
#include <hip/hip_runtime.h>

// B=8, N=M=4096, D=3, fp32 in/out.
constexpr int B = 8;
constexpr int N = 4096;           // == M
constexpr int PTS = B * N;        // 32768 points per cloud
constexpr int TOT = 2 * PTS;      // 65536 (both directions)

#define TPB 256                   // threads per block
#define R 4                       // own points per thread -> 1024 own pts/block
#define CHUNK 128                 // other points per block (2 KB LDS as float4)
#define NCHUNK (N / CHUNK)        // 32
#define NTILE (N / (TPB * R))     // 4

// Phase 0: build q-precomp arrays float4(qx,qy,qz,|q|^2).
// qpre[0][p] from y1 (the "other" cloud for dir 0), qpre[1][p] from x1.
// Thread 0 also zeroes d_out (poisoned 0xAA each call).
__global__ __launch_bounds__(256) void prep(
        const float* __restrict__ x1, const float* __restrict__ y1,
        float4* __restrict__ qpre, float* __restrict__ out) {
    int tid = blockIdx.x * 256 + threadIdx.x;
    if (tid == 0) out[0] = 0.0f;
    if (tid >= TOT) return;
    int dir = tid >> 15;               // 0: from y1, 1: from x1
    int p   = tid & (PTS - 1);
    const float* src = dir ? x1 : y1;
    float qx = src[3 * p], qy = src[3 * p + 1], qz = src[3 * p + 2];
    float qq = fmaf(qx, qx, fmaf(qy, qy, qz * qz));
    qpre[tid] = make_float4(qx, qy, qz, qq);
}

// Phase 1: per (dir, batch, own-tile, chunk) compute min over the chunk of
// the Gram form; plain store of clamped d2 into partials[chunk][dirpoint].
__global__ __launch_bounds__(TPB) void chamfer_min3(
        const float* __restrict__ x1, const float* __restrict__ y1,
        const float4* __restrict__ qpre,
        float* __restrict__ partials) {      // [NCHUNK][TOT]
    __shared__ float4 qs[CHUNK];

    const int dir   = blockIdx.y / NCHUNK;
    const int chunk = blockIdx.y % NCHUNK;
    const int b     = blockIdx.z;
    const int tile  = blockIdx.x;

    // Stage CHUNK preprocessed other-points (one coalesced float4 load).
    const float4* qp = qpre + (size_t)dir * PTS + (size_t)b * N + chunk * CHUNK;
    if (threadIdx.x < CHUNK) qs[threadIdx.x] = qp[threadIdx.x];

    // R own points, strided by TPB.
    const float* own = dir ? y1 : x1;
    const int ibase = tile * (TPB * R) + threadIdx.x;
    float mx[R], my[R], mz[R], xx[R], acc[R];
    #pragma unroll
    for (int r = 0; r < R; r++) {
        const float* pp = own + ((size_t)b * N + ibase + r * TPB) * 3;
        float px = pp[0], py = pp[1], pz = pp[2];
        mx[r] = -2.0f * px; my[r] = -2.0f * py; mz[r] = -2.0f * pz;
        xx[r] = fmaf(px, px, fmaf(py, py, pz * pz));
        acc[r] = 3.4e38f;
    }

    __syncthreads();

    // min_j (|q|^2 - 2 x.q) : 3 FMA + 1 min per pair.
    #pragma unroll 4
    for (int j = 0; j < CHUNK; j++) {
        float4 q = qs[j];
        #pragma unroll
        for (int r = 0; r < R; r++) {
            float g = fmaf(mx[r], q.x, fmaf(my[r], q.y, fmaf(mz[r], q.z, q.w)));
            acc[r] = fminf(acc[r], g);
        }
    }

    // Coalesced partial stores: point index p in [0, TOT).
    float* dst = partials + (size_t)chunk * TOT + (size_t)dir * PTS + (size_t)b * N;
    #pragma unroll
    for (int r = 0; r < R; r++) {
        dst[ibase + r * TPB] = fmaxf(acc[r] + xx[r], 0.0f);
    }
}

// Phase 2: per point, min over NCHUNK partials; sqrt; block-sum; one
// atomicAdd per block into the (already zeroed) scalar output.
__global__ __launch_bounds__(256) void chamfer_finish(
        const float* __restrict__ partials, float* __restrict__ out, float scale) {
    int p = blockIdx.x * 256 + threadIdx.x;   // [0, TOT)
    float m = partials[p];
    #pragma unroll
    for (int c = 1; c < NCHUNK; c++) m = fminf(m, partials[(size_t)c * TOT + p]);
    float s = sqrtf(1e-8f + m) * scale;

    #pragma unroll
    for (int off = 32; off > 0; off >>= 1) s += __shfl_down(s, off, 64);

    __shared__ float partial[4];
    const int wid = threadIdx.x >> 6, lane = threadIdx.x & 63;
    if (lane == 0) partial[wid] = s;
    __syncthreads();
    if (threadIdx.x == 0) {
        atomicAdd(out, partial[0] + partial[1] + partial[2] + partial[3]);
    }
}

extern "C" void kernel_launch(void* const* d_in, const int* in_sizes, int n_in,
                              void* d_out, int out_size, void* d_ws, size_t ws_size,
                              hipStream_t stream) {
    const float* x1 = (const float*)d_in[0];   // (B, N, 3)
    const float* y1 = (const float*)d_in[1];   // (B, N, 3)
    float* out = (float*)d_out;

    float4* qpre    = (float4*)d_ws;                    // TOT float4 = 1 MB
    float* partials = (float*)(qpre + TOT);             // NCHUNK*TOT = 8 MB

    prep<<<TOT / 256, 256, 0, stream>>>(x1, y1, qpre, out);

    dim3 grid(NTILE, 2 * NCHUNK, B);                    // 4 x 64 x 8 = 2048 blocks
    chamfer_min3<<<grid, TPB, 0, stream>>>(x1, y1, qpre, partials);

    chamfer_finish<<<TOT / 256, 256, 0, stream>>>(partials, out, 1.0f / (B * N));
}

// Round 4
// 82.752 us; speedup vs baseline: 1.7052x; 1.0234x over previous
//
#include <hip/hip_runtime.h>

// B=8, N=M=4096, D=3, fp32 in/out.
constexpr int B = 8;
constexpr int N = 4096;           // == M
constexpr int PTS = B * N;        // 32768 points per cloud
constexpr int TOT = 2 * PTS;      // 65536 (both directions)

#define TPB 256                   // threads per block
#define R 8                       // own points per thread
#define RP (R / 2)                // packed float2 pairs per thread
#define CHUNK 128                 // other points staged per block (2 KB LDS)
#define KC (N / CHUNK)            // 32 chunks
#define NTILE (N / (TPB * R))     // 2 own-tiles per (dir, batch)

typedef float float2v __attribute__((ext_vector_type(2)));

// Phase 1: per (dir, batch, tile, chunk): min over the chunk of the Gram form
//   d2_partial = min_j (|q_j|^2 - 2 p.q_j), finished with + |p|^2, clamp >= 0.
// Inner loop uses v_pk_fma_f32 (packed fp32, 2 FMA/lane/instr) via inline asm:
// q components are broadcast into both halves with op_sel/op_sel_hi, so per 2
// own-points it's 3 pk_fma + 2 v_min = 2.5 VALU instr per pair.
__global__ __launch_bounds__(TPB) void chamfer_min4(
        const float* __restrict__ x1, const float* __restrict__ y1,
        float* __restrict__ partials,      // [KC][TOT]
        float* __restrict__ out) {
    __shared__ float4 qs[CHUNK];

    // Zero the output scalar once per launch (d_out is poisoned 0xAA).
    // Kernel-boundary ordering guarantees this lands before chamfer_finish.
    if (blockIdx.x == 0 && blockIdx.y == 0 && blockIdx.z == 0 && threadIdx.x == 0)
        out[0] = 0.0f;

    const int dir   = blockIdx.y / KC;
    const int chunk = blockIdx.y % KC;
    const int b     = blockIdx.z;
    const int tile  = blockIdx.x;

    const float* own = dir ? y1 : x1;
    const float* oth = dir ? x1 : y1;

    // Stage CHUNK other-points as float4(qx,qy,qz,|q|^2) (prep fused here).
    if (threadIdx.x < CHUNK) {
        const float* op = oth + ((size_t)b * N + chunk * CHUNK + threadIdx.x) * 3;
        float qx = op[0], qy = op[1], qz = op[2];
        qs[threadIdx.x] = make_float4(qx, qy, qz, fmaf(qx, qx, fmaf(qy, qy, qz * qz)));
    }

    // R own points per thread, strided by TPB; coefficients packed in pairs.
    const int ibase = tile * (TPB * R) + threadIdx.x;
    float2v mx2[RP], my2[RP], mz2[RP], acc2[RP];
    float xx[R];
    #pragma unroll
    for (int p = 0; p < RP; p++) {
        #pragma unroll
        for (int e = 0; e < 2; e++) {
            const int r = 2 * p + e;
            const float* pp = own + ((size_t)b * N + ibase + r * TPB) * 3;
            float px = pp[0], py = pp[1], pz = pp[2];
            mx2[p][e] = -2.0f * px;
            my2[p][e] = -2.0f * py;
            mz2[p][e] = -2.0f * pz;
            xx[r] = fmaf(px, px, fmaf(py, py, pz * pz));
        }
        acc2[p] = float2v{3.4e38f, 3.4e38f};
    }

    __syncthreads();

    #pragma unroll 2
    for (int j = 0; j < CHUNK; j++) {
        union { float4 f4; float2v f2[2]; } qa;
        qa.f4 = qs[j];                 // one ds_read_b128, broadcast (no conflicts)
        float2v xy = qa.f2[0];         // (q.x lo, q.y hi)
        float2v zw = qa.f2[1];         // (q.z lo, q.w hi)
        #pragma unroll
        for (int p = 0; p < RP; p++) {
            float2v g;
            // g = q.z * mz2 + q.w   (q.z -> both halves; q.w -> both halves)
            asm("v_pk_fma_f32 %0, %1, %2, %1 op_sel:[0,0,1] op_sel_hi:[0,1,1]"
                : "=v"(g) : "v"(zw), "v"(mz2[p]));
            // g = q.y * my2 + g     (q.y = hi half of xy -> both halves)
            asm("v_pk_fma_f32 %0, %1, %2, %3 op_sel:[1,0,0] op_sel_hi:[1,1,1]"
                : "=v"(g) : "v"(xy), "v"(my2[p]), "v"(g));
            // g = q.x * mx2 + g     (q.x = lo half of xy -> both halves)
            asm("v_pk_fma_f32 %0, %1, %2, %3 op_sel:[0,0,0] op_sel_hi:[0,1,1]"
                : "=v"(g) : "v"(xy), "v"(mx2[p]), "v"(g));
            acc2[p].x = fminf(acc2[p].x, g.x);
            acc2[p].y = fminf(acc2[p].y, g.y);
        }
    }

    // Coalesced partial stores.
    float* dst = partials + (size_t)chunk * TOT + (size_t)dir * PTS + (size_t)b * N;
    #pragma unroll
    for (int p = 0; p < RP; p++) {
        dst[ibase + (2 * p) * TPB]     = fmaxf(acc2[p].x + xx[2 * p], 0.0f);
        dst[ibase + (2 * p + 1) * TPB] = fmaxf(acc2[p].y + xx[2 * p + 1], 0.0f);
    }
}

// Phase 2: per point min over KC partials; sqrt; block-sum; one atomicAdd/block.
__global__ __launch_bounds__(256) void chamfer_finish(
        const float* __restrict__ partials, float* __restrict__ out, float scale) {
    int p = blockIdx.x * 256 + threadIdx.x;   // [0, TOT)
    float m = partials[p];
    #pragma unroll
    for (int c = 1; c < KC; c++) m = fminf(m, partials[(size_t)c * TOT + p]);
    float s = sqrtf(1e-8f + m) * scale;

    #pragma unroll
    for (int off = 32; off > 0; off >>= 1) s += __shfl_down(s, off, 64);

    __shared__ float partial[4];
    const int wid = threadIdx.x >> 6, lane = threadIdx.x & 63;
    if (lane == 0) partial[wid] = s;
    __syncthreads();
    if (threadIdx.x == 0) {
        atomicAdd(out, partial[0] + partial[1] + partial[2] + partial[3]);
    }
}

extern "C" void kernel_launch(void* const* d_in, const int* in_sizes, int n_in,
                              void* d_out, int out_size, void* d_ws, size_t ws_size,
                              hipStream_t stream) {
    const float* x1 = (const float*)d_in[0];   // (B, N, 3)
    const float* y1 = (const float*)d_in[1];   // (B, N, 3)
    float* out = (float*)d_out;

    float* partials = (float*)d_ws;            // KC * TOT floats = 8 MB

    dim3 grid(NTILE, 2 * KC, B);               // 2 x 64 x 8 = 1024 blocks
    chamfer_min4<<<grid, TPB, 0, stream>>>(x1, y1, partials, out);

    chamfer_finish<<<TOT / 256, 256, 0, stream>>>(partials, out, 1.0f / (B * N));
}

// Round 5
// 82.106 us; speedup vs baseline: 1.7187x; 1.0079x over previous
//
#include <hip/hip_runtime.h>

// B=8, N=M=4096, D=3, fp32 in/out.
constexpr int B = 8;
constexpr int N = 4096;           // == M
constexpr int PTS = B * N;        // 32768 points per cloud
constexpr int TOT = 2 * PTS;      // 65536 (both directions)

#define TPB 256                   // threads per block
#define R 16                      // own points per thread -> TPB*R = 4096 = N
#define RP (R / 2)                // packed float2 pairs per thread
#define CHUNK 128                 // other points staged per block (2 KB LDS)
#define KC (N / CHUNK)            // 32 chunks

typedef float float2v __attribute__((ext_vector_type(2)));

// Phase 1: block = (chunk, dir, batch). Each block holds ALL N own points of
// its (dir,b) across 256 threads x R=16, and min-reduces over one CHUNK of
// other points using the Gram form  g = |q|^2 - 2 p.q  (|p|^2 added at the
// end, clamped >= 0 like the reference).
// Inner loop: v_pk_fma_f32 (2 FMA/instr) with q broadcast via op_sel, and
// 2-j min3 folding (v_min3_f32) -> (48 pk_fma + 16 min3) per 2 j's per wave.
__global__ __launch_bounds__(TPB) void chamfer_min5(
        const float* __restrict__ x1, const float* __restrict__ y1,
        float* __restrict__ partials,      // [KC][TOT]
        float* __restrict__ out) {
    __shared__ float4 qs[CHUNK];

    // Zero the output scalar once per launch (d_out is poisoned 0xAA).
    if (blockIdx.x == 0 && blockIdx.y == 0 && blockIdx.z == 0 && threadIdx.x == 0)
        out[0] = 0.0f;

    const int chunk = blockIdx.x;
    const int dir   = blockIdx.y;
    const int b     = blockIdx.z;

    const float* own = dir ? y1 : x1;
    const float* oth = dir ? x1 : y1;

    // Stage CHUNK other-points as float4(qx,qy,qz,|q|^2).
    if (threadIdx.x < CHUNK) {
        const float* op = oth + ((size_t)b * N + chunk * CHUNK + threadIdx.x) * 3;
        float qx = op[0], qy = op[1], qz = op[2];
        qs[threadIdx.x] = make_float4(qx, qy, qz, fmaf(qx, qx, fmaf(qy, qy, qz * qz)));
    }

    // R own points per thread, strided by TPB; coefficients packed in pairs.
    float2v mx2[RP], my2[RP], mz2[RP], acc2[RP];
    float xx[R];
    #pragma unroll
    for (int p = 0; p < RP; p++) {
        #pragma unroll
        for (int e = 0; e < 2; e++) {
            const int r = 2 * p + e;
            const float* pp = own + ((size_t)b * N + threadIdx.x + r * TPB) * 3;
            float px = pp[0], py = pp[1], pz = pp[2];
            mx2[p][e] = -2.0f * px;
            my2[p][e] = -2.0f * py;
            mz2[p][e] = -2.0f * pz;
            xx[r] = fmaf(px, px, fmaf(py, py, pz * pz));
        }
        acc2[p] = float2v{3.4e38f, 3.4e38f};
    }

    __syncthreads();

    #pragma unroll 2
    for (int j = 0; j < CHUNK; j += 2) {
        union { float4 f4; float2v f2[2]; } qa0, qa1;
        qa0.f4 = qs[j];                // ds_read_b128, broadcast
        qa1.f4 = qs[j + 1];
        float2v xy0 = qa0.f2[0], zw0 = qa0.f2[1];
        float2v xy1 = qa1.f2[0], zw1 = qa1.f2[1];
        #pragma unroll
        for (int p = 0; p < RP; p++) {
            float2v g0, g1;
            // g = q.z * mz + q.w  (q.z, q.w broadcast to both halves)
            asm("v_pk_fma_f32 %0, %1, %2, %1 op_sel:[0,0,1] op_sel_hi:[0,1,1]"
                : "=v"(g0) : "v"(zw0), "v"(mz2[p]));
            asm("v_pk_fma_f32 %0, %1, %2, %1 op_sel:[0,0,1] op_sel_hi:[0,1,1]"
                : "=v"(g1) : "v"(zw1), "v"(mz2[p]));
            // g = q.y * my + g   (q.y = hi half, broadcast)
            asm("v_pk_fma_f32 %0, %1, %2, %3 op_sel:[1,0,0] op_sel_hi:[1,1,1]"
                : "=v"(g0) : "v"(xy0), "v"(my2[p]), "v"(g0));
            asm("v_pk_fma_f32 %0, %1, %2, %3 op_sel:[1,0,0] op_sel_hi:[1,1,1]"
                : "=v"(g1) : "v"(xy1), "v"(my2[p]), "v"(g1));
            // g = q.x * mx + g   (q.x = lo half, broadcast)
            asm("v_pk_fma_f32 %0, %1, %2, %3 op_sel:[0,0,0] op_sel_hi:[0,1,1]"
                : "=v"(g0) : "v"(xy0), "v"(mx2[p]), "v"(g0));
            asm("v_pk_fma_f32 %0, %1, %2, %3 op_sel:[0,0,0] op_sel_hi:[0,1,1]"
                : "=v"(g1) : "v"(xy1), "v"(mx2[p]), "v"(g1));
            // 2-j fold: v_min3_f32 per half.
            acc2[p].x = fminf(fminf(acc2[p].x, g0.x), g1.x);
            acc2[p].y = fminf(fminf(acc2[p].y, g0.y), g1.y);
        }
    }

    // Coalesced partial stores.
    float* dst = partials + (size_t)chunk * TOT + (size_t)dir * PTS + (size_t)b * N;
    #pragma unroll
    for (int p = 0; p < RP; p++) {
        dst[threadIdx.x + (2 * p) * TPB]     = fmaxf(acc2[p].x + xx[2 * p], 0.0f);
        dst[threadIdx.x + (2 * p + 1) * TPB] = fmaxf(acc2[p].y + xx[2 * p + 1], 0.0f);
    }
}

// Phase 2: per point min over KC partials; sqrt; block-sum; one atomicAdd/block.
__global__ __launch_bounds__(256) void chamfer_finish(
        const float* __restrict__ partials, float* __restrict__ out, float scale) {
    int p = blockIdx.x * 256 + threadIdx.x;   // [0, TOT)
    float m = partials[p];
    #pragma unroll
    for (int c = 1; c < KC; c++) m = fminf(m, partials[(size_t)c * TOT + p]);
    float s = sqrtf(1e-8f + m) * scale;

    #pragma unroll
    for (int off = 32; off > 0; off >>= 1) s += __shfl_down(s, off, 64);

    __shared__ float partial[4];
    const int wid = threadIdx.x >> 6, lane = threadIdx.x & 63;
    if (lane == 0) partial[wid] = s;
    __syncthreads();
    if (threadIdx.x == 0) {
        atomicAdd(out, partial[0] + partial[1] + partial[2] + partial[3]);
    }
}

extern "C" void kernel_launch(void* const* d_in, const int* in_sizes, int n_in,
                              void* d_out, int out_size, void* d_ws, size_t ws_size,
                              hipStream_t stream) {
    const float* x1 = (const float*)d_in[0];   // (B, N, 3)
    const float* y1 = (const float*)d_in[1];   // (B, N, 3)
    float* out = (float*)d_out;

    float* partials = (float*)d_ws;            // KC * TOT floats = 8 MB

    dim3 grid(KC, 2, B);                       // 32 x 2 x 8 = 512 blocks
    chamfer_min5<<<grid, TPB, 0, stream>>>(x1, y1, partials, out);

    chamfer_finish<<<TOT / 256, 256, 0, stream>>>(partials, out, 1.0f / (B * N));
}